// Round 1
// baseline (123.318 us; speedup 1.0000x reference)
//
#include <hip/hip_runtime.h>

// ---------------------------------------------------------------------------
// KAN conv layer: out[b,o,i,j] = sum_{c,p} silu(patch)*bw[o,c,p]
//                              + sum_{c,p,g} Bspline_g(patch)*sw[o,c,p,g]*sc[o,c,p]
// B=16 CIN=32 COUT=64 H=W=64 K=3 -> Ho=Wo=62, P=9, G+k=8 bases
// Strategy: per-input-pixel features (silu + 8 bases) in bf16, then implicit
// GEMM with MFMA 16x16x32_bf16. K = 32c*(24 spline + 9 silu) = 2592 = 81*32.
// Feature layouts chosen so every MFMA fragment is one aligned 16B global load:
//   Fspl[b][c][y][x][g8]  (16 B / pixel)   spline part, chunks of 24 per (c,di)
//   Fsil[b][y][x][c32]    (64 B / pixel)   base part, chunks of 32 per tap
//   Wpack: weights in exact A-fragment order (lane*16B per step/o-tile)
// ---------------------------------------------------------------------------

typedef short v8s __attribute__((ext_vector_type(8)));
typedef float v4f __attribute__((ext_vector_type(4)));

#define FSPL_OFF   0u
#define FSILU_OFF  33554688u          // 33554432 (Fspl) + 256 pad
#define WPACK_OFF  37749248u          // FSILU_OFF + 4194304 (Fsil) + 256 pad
// total workspace need: 37749248 + 331776 = 38,081,024 bytes (~38.1 MB)

__device__ __forceinline__ unsigned short f2bf(float f) {
  unsigned int u = __float_as_uint(f);
  u += 0x7fffu + ((u >> 16) & 1u);          // round-to-nearest-even
  return (unsigned short)(u >> 16);
}

// ---- kernel 1: spline bases per input element -> Fspl[b][c][y][x][g8] ------
__global__ __launch_bounds__(256) void k_spline(const float* __restrict__ x,
                                                unsigned char* __restrict__ ws) {
  int pix = blockIdx.x * 256 + threadIdx.x;      // 16*32*64*64 = 2,097,152
  float v = x[pix];
  float bb[11];
#pragma unroll
  for (int i = 0; i < 11; ++i) {
    float t0 = -2.2f + 0.4f * i;                 // knots: -1 + (i-3)*0.4
    bb[i] = (v >= t0 && v < t0 + 0.4f) ? 1.0f : 0.0f;
  }
#pragma unroll
  for (int j = 1; j <= 3; ++j) {
    float rj = 1.0f / (0.4f * j);
#pragma unroll
    for (int i = 0; i + j < 11; ++i) {
      float ti = -2.2f + 0.4f * i;
      float lf = (v - ti) * rj;
      float rt = ((ti + 0.4f * (j + 1)) - v) * rj;
      bb[i] = lf * bb[i] + rt * bb[i + 1];
    }
  }
  uint4 o;
  o.x = (unsigned)f2bf(bb[0]) | ((unsigned)f2bf(bb[1]) << 16);
  o.y = (unsigned)f2bf(bb[2]) | ((unsigned)f2bf(bb[3]) << 16);
  o.z = (unsigned)f2bf(bb[4]) | ((unsigned)f2bf(bb[5]) << 16);
  o.w = (unsigned)f2bf(bb[6]) | ((unsigned)f2bf(bb[7]) << 16);
  *(uint4*)(ws + FSPL_OFF + (size_t)pix * 16) = o;
}

// ---- kernel 2: silu, transposed -> Fsil[b][y][x][c32] ----------------------
__global__ __launch_bounds__(256) void k_silu(const float* __restrict__ x,
                                              unsigned char* __restrict__ ws) {
  int bid = blockIdx.x;                  // b*64 + y  (1024 blocks)
  int b = bid >> 6, y = bid & 63;
  int t = threadIdx.x;
  int xx = t & 63, cg = t >> 6;          // cg: 8-channel group 0..3
  unsigned short h[8];
#pragma unroll
  for (int k = 0; k < 8; ++k) {
    int c = cg * 8 + k;
    float v = x[(((size_t)(b * 32 + c) * 64 + y) * 64) + xx];
    float s = v / (1.0f + __expf(-v));
    h[k] = f2bf(s);
  }
  uint4 o;
  o.x = (unsigned)h[0] | ((unsigned)h[1] << 16);
  o.y = (unsigned)h[2] | ((unsigned)h[3] << 16);
  o.z = (unsigned)h[4] | ((unsigned)h[5] << 16);
  o.w = (unsigned)h[6] | ((unsigned)h[7] << 16);
  *(uint4*)(ws + FSILU_OFF + (size_t)(b * 4096 + y * 64 + xx) * 64 + cg * 16) = o;
}

// ---- kernel 3: pack weights in MFMA A-fragment order -----------------------
// Wpack[s][ot][lane][e] = W[k = 32s + (lane>>4)*8 + e][o = ot*16 + (lane&15)]
// k<2304: spline, chunk=k/24 (c=chunk/3,di=chunk%3), u=k%24 (dj=u>>3,g=u&7)
// k>=2304: base,  k2=k-2304: tap t=k2>>5 (=p), cc=k2&31
__global__ __launch_bounds__(256) void k_wpack(const float* __restrict__ bw,
                                               const float* __restrict__ sw,
                                               const float* __restrict__ sc,
                                               unsigned char* __restrict__ ws) {
  int tid = blockIdx.x * 256 + threadIdx.x;
  if (tid >= 165888) return;             // 81*4*64*8
  int e = tid & 7, lane = (tid >> 3) & 63, ot = (tid >> 9) & 3, s = tid >> 11;
  int k = s * 32 + ((lane >> 4) << 3) + e;
  int o = (ot << 4) + (lane & 15);
  float val;
  if (k < 2304) {
    int chunk = k / 24, u = k - chunk * 24;
    int dj = u >> 3, g = u & 7;
    int c = chunk / 3, di = chunk - c * 3;
    int p = di * 3 + dj;
    val = sw[((size_t)(o * 32 + c) * 9 + p) * 8 + g] * sc[(size_t)(o * 32 + c) * 9 + p];
  } else {
    int k2 = k - 2304;
    int tp = k2 >> 5, cc = k2 & 31;
    val = bw[(size_t)(o * 32 + cc) * 9 + tp];
  }
  *(unsigned short*)(ws + WPACK_OFF + (size_t)tid * 2) = f2bf(val);
}

// ---- kernel 4: implicit GEMM, one wave per (b, i) output row ---------------
// wave tile: 64 o x 64 j, 4x4 grid of 16x16 MFMA tiles, K = 81 steps of 32.
// A-operand = weights (m=o), B-operand = features (n=j) -> coalesced C stores.
__global__ __launch_bounds__(64, 1) void k_gemm(const unsigned char* __restrict__ ws,
                                                float* __restrict__ out) {
  const int blk = blockIdx.x;            // b*62 + i   (992 blocks)
  const int b = blk / 62, i = blk - b * 62;
  const int lane = threadIdx.x;
  const int q = lane >> 4, ln = lane & 15;

  const unsigned char* fspl = ws + FSPL_OFF;
  const unsigned char* fsil = ws + FSILU_OFF;
  const unsigned char* wp   = ws + WPACK_OFF + (size_t)lane * 16;

  // per-lane spline feature offsets for the 9 steps of each period
  // run rid = 4*sg + q; chunk_off = rid/3; sub = rid%3; c_off = chunk_off/3;
  // di = chunk_off%3.  plane stride 65536 B, row stride 1024 B, pixel 16 B.
  int voff[9];
#pragma unroll
  for (int sg = 0; sg < 9; ++sg) {
    int rid = 4 * sg + q;
    int ch = rid / 3;
    int sub = rid - ch * 3;
    int coff = ch / 3;
    int di = ch - coff * 3;
    voff[sg] = coff * 65536 + di * 1024 + sub * 16 + ln * 16;
  }

  v4f acc[4][4];
#pragma unroll
  for (int a = 0; a < 4; ++a)
#pragma unroll
    for (int c = 0; c < 4; ++c) acc[a][c] = (v4f){0.f, 0.f, 0.f, 0.f};

  v8s wb[3][4], fb[3][4];
  const unsigned char* sb = fspl + (size_t)(b * 2048 + i) * 1024;  // period-0 base

  // ---- spline phase: 72 steps (8 periods x 9), 3-step prefetch pipeline ----
#pragma unroll
  for (int sg = 0; sg < 3; ++sg) {       // prologue: steps 0,1,2
#pragma unroll
    for (int ot = 0; ot < 4; ++ot) wb[sg][ot] = *(const v8s*)(wp + sg * 4096 + ot * 1024);
    const unsigned char* p = sb + voff[sg];
#pragma unroll
    for (int pt = 0; pt < 4; ++pt) fb[sg][pt] = *(const v8s*)(p + pt * 256);
  }

  for (int t = 0; t < 8; ++t) {
#pragma unroll
    for (int sg = 0; sg < 9; ++sg) {
      const int bufi = sg % 3;
#pragma unroll
      for (int ot = 0; ot < 4; ++ot)
#pragma unroll
        for (int pt = 0; pt < 4; ++pt)
          acc[ot][pt] = __builtin_amdgcn_mfma_f32_16x16x32_bf16(
              wb[bufi][ot], fb[bufi][pt], acc[ot][pt], 0, 0, 0);
      const int s_next = t * 9 + sg + 3;
      if (s_next < 72) {
#pragma unroll
        for (int ot = 0; ot < 4; ++ot)
          wb[bufi][ot] = *(const v8s*)(wp + (size_t)s_next * 4096 + ot * 1024);
        const int nsg = (sg + 3 < 9) ? sg + 3 : sg - 6;      // compile-time
        const unsigned char* p = ((sg + 3 < 9) ? sb : sb + 262144) + voff[nsg];
#pragma unroll
        for (int pt = 0; pt < 4; ++pt) fb[bufi][pt] = *(const v8s*)(p + pt * 256);
      }
    }
    sb += 262144;                        // 4 c-planes per period
  }

  // ---- silu phase: 9 steps (s = 72..80), tap = step index ------------------
#pragma unroll
  for (int sg = 0; sg < 3; ++sg) {       // prologue: steps 72,73,74
#pragma unroll
    for (int ot = 0; ot < 4; ++ot)
      wb[sg][ot] = *(const v8s*)(wp + (size_t)(72 + sg) * 4096 + ot * 1024);
    const int di = sg / 3, dj = sg - 3 * (sg / 3);
    const unsigned char* p =
        fsil + (size_t)((b * 64 + i + di) * 64 + dj) * 64 + ln * 64 + q * 16;
#pragma unroll
    for (int pt = 0; pt < 4; ++pt) fb[sg][pt] = *(const v8s*)(p + pt * 1024);
  }
#pragma unroll
  for (int sg = 0; sg < 9; ++sg) {
    const int bufi = sg % 3;
#pragma unroll
    for (int ot = 0; ot < 4; ++ot)
#pragma unroll
      for (int pt = 0; pt < 4; ++pt)
        acc[ot][pt] = __builtin_amdgcn_mfma_f32_16x16x32_bf16(
            wb[bufi][ot], fb[bufi][pt], acc[ot][pt], 0, 0, 0);
    if (sg + 3 < 9) {
      const int s2 = sg + 3;
#pragma unroll
      for (int ot = 0; ot < 4; ++ot)
        wb[bufi][ot] = *(const v8s*)(wp + (size_t)(72 + s2) * 4096 + ot * 1024);
      const int di = s2 / 3, dj = s2 - 3 * (s2 / 3);
      const unsigned char* p =
          fsil + (size_t)((b * 64 + i + di) * 64 + dj) * 64 + ln * 64 + q * 16;
#pragma unroll
      for (int pt = 0; pt < 4; ++pt) fb[bufi][pt] = *(const v8s*)(p + pt * 1024);
    }
  }

  // ---- epilogue: C/D layout col(n=j)=lane&15, row(m=o)=q*4+reg -------------
#pragma unroll
  for (int ot = 0; ot < 4; ++ot)
#pragma unroll
    for (int pt = 0; pt < 4; ++pt) {
      const int j = pt * 16 + ln;
      if (j < 62) {
#pragma unroll
        for (int r = 0; r < 4; ++r) {
          const int o = ot * 16 + q * 4 + r;
          out[(((size_t)b * 64 + o) * 62 + i) * 62 + j] = acc[ot][pt][r];
        }
      }
    }
}

extern "C" void kernel_launch(void* const* d_in, const int* in_sizes, int n_in,
                              void* d_out, int out_size, void* d_ws, size_t ws_size,
                              hipStream_t stream) {
  const float* x  = (const float*)d_in[0];
  const float* bw = (const float*)d_in[1];
  const float* sw = (const float*)d_in[2];
  const float* sc = (const float*)d_in[3];
  unsigned char* ws = (unsigned char*)d_ws;
  float* out = (float*)d_out;

  hipLaunchKernelGGL(k_spline, dim3(8192), dim3(256), 0, stream, x, ws);
  hipLaunchKernelGGL(k_silu,   dim3(1024), dim3(256), 0, stream, x, ws);
  hipLaunchKernelGGL(k_wpack,  dim3(648),  dim3(256), 0, stream, bw, sw, sc, ws);
  hipLaunchKernelGGL(k_gemm,   dim3(992),  dim3(64),  0, stream, ws, out);
}

// Round 2
// 119.077 us; speedup vs baseline: 1.0356x; 1.0356x over previous
//
#include <hip/hip_runtime.h>

// ---------------------------------------------------------------------------
// KAN conv layer: out[b,o,i,j] = sum_{c,p} silu(patch)*bw[o,c,p]
//                              + sum_{c,p,g} Bspline_g(patch)*sw[o,c,p,g]*sc[o,c,p]
// B=16 CIN=32 COUT=64 H=W=64 K=3 -> Ho=Wo=62, P=9, G+k=8 bases
// bf16 MFMA implicit GEMM, K = 2592 = 81 steps of 32.
// R2: in-block split-K — 4 waves/block, wave w does spline periods {2w,2w+1}
//     (+3 silu steps for w<3); LDS tree-reduction. 3968 waves (~4/SIMD) at
//     unchanged L2 traffic. No main-loop barriers.
// ---------------------------------------------------------------------------

typedef short v8s __attribute__((ext_vector_type(8)));
typedef float v4f __attribute__((ext_vector_type(4)));

#define FSPL_OFF   0u
#define FSILU_OFF  33554688u          // 33554432 (Fspl) + 256 pad
#define WPACK_OFF  37749248u          // FSILU_OFF + 4194304 (Fsil) + 256 pad

__device__ __forceinline__ unsigned short f2bf(float f) {
  unsigned int u = __float_as_uint(f);
  u += 0x7fffu + ((u >> 16) & 1u);          // round-to-nearest-even
  return (unsigned short)(u >> 16);
}

// ---- kernel 1: spline bases per input element -> Fspl[b][c][y][x][g8] ------
__global__ __launch_bounds__(256) void k_spline(const float* __restrict__ x,
                                                unsigned char* __restrict__ ws) {
  int pix = blockIdx.x * 256 + threadIdx.x;      // 2,097,152 elements
  float v = x[pix];
  float bb[11];
#pragma unroll
  for (int i = 0; i < 11; ++i) {
    float t0 = -2.2f + 0.4f * i;
    bb[i] = (v >= t0 && v < t0 + 0.4f) ? 1.0f : 0.0f;
  }
#pragma unroll
  for (int j = 1; j <= 3; ++j) {
    float rj = 1.0f / (0.4f * j);
#pragma unroll
    for (int i = 0; i + j < 11; ++i) {
      float ti = -2.2f + 0.4f * i;
      float lf = (v - ti) * rj;
      float rt = ((ti + 0.4f * (j + 1)) - v) * rj;
      bb[i] = lf * bb[i] + rt * bb[i + 1];
    }
  }
  uint4 o;
  o.x = (unsigned)f2bf(bb[0]) | ((unsigned)f2bf(bb[1]) << 16);
  o.y = (unsigned)f2bf(bb[2]) | ((unsigned)f2bf(bb[3]) << 16);
  o.z = (unsigned)f2bf(bb[4]) | ((unsigned)f2bf(bb[5]) << 16);
  o.w = (unsigned)f2bf(bb[6]) | ((unsigned)f2bf(bb[7]) << 16);
  *(uint4*)(ws + FSPL_OFF + (size_t)pix * 16) = o;
}

// ---- kernel 2: silu, transposed -> Fsil[b][y][x][c32] ----------------------
__global__ __launch_bounds__(256) void k_silu(const float* __restrict__ x,
                                              unsigned char* __restrict__ ws) {
  int bid = blockIdx.x;                  // b*64 + y
  int b = bid >> 6, y = bid & 63;
  int t = threadIdx.x;
  int xx = t & 63, cg = t >> 6;
  unsigned short h[8];
#pragma unroll
  for (int k = 0; k < 8; ++k) {
    int c = cg * 8 + k;
    float v = x[(((size_t)(b * 32 + c) * 64 + y) * 64) + xx];
    float s = v / (1.0f + __expf(-v));
    h[k] = f2bf(s);
  }
  uint4 o;
  o.x = (unsigned)h[0] | ((unsigned)h[1] << 16);
  o.y = (unsigned)h[2] | ((unsigned)h[3] << 16);
  o.z = (unsigned)h[4] | ((unsigned)h[5] << 16);
  o.w = (unsigned)h[6] | ((unsigned)h[7] << 16);
  *(uint4*)(ws + FSILU_OFF + (size_t)(b * 4096 + y * 64 + xx) * 64 + cg * 16) = o;
}

// ---- kernel 3: pack weights in MFMA A-fragment order -----------------------
__global__ __launch_bounds__(256) void k_wpack(const float* __restrict__ bw,
                                               const float* __restrict__ sw,
                                               const float* __restrict__ sc,
                                               unsigned char* __restrict__ ws) {
  int tid = blockIdx.x * 256 + threadIdx.x;
  if (tid >= 165888) return;             // 81*4*64*8
  int e = tid & 7, lane = (tid >> 3) & 63, ot = (tid >> 9) & 3, s = tid >> 11;
  int k = s * 32 + ((lane >> 4) << 3) + e;
  int o = (ot << 4) + (lane & 15);
  float val;
  if (k < 2304) {
    int chunk = k / 24, u = k - chunk * 24;
    int dj = u >> 3, g = u & 7;
    int c = chunk / 3, di = chunk - c * 3;
    int p = di * 3 + dj;
    val = sw[((size_t)(o * 32 + c) * 9 + p) * 8 + g] * sc[(size_t)(o * 32 + c) * 9 + p];
  } else {
    int k2 = k - 2304;
    int tp = k2 >> 5, cc = k2 & 31;
    val = bw[(size_t)(o * 32 + cc) * 9 + tp];
  }
  *(unsigned short*)(ws + WPACK_OFF + (size_t)tid * 2) = f2bf(val);
}

// ---- kernel 4: implicit GEMM, split-K over 4 waves per (b,i) row -----------
__global__ __launch_bounds__(256, 4) void k_gemm(const unsigned char* __restrict__ ws,
                                                 float* __restrict__ out) {
  const int blk = blockIdx.x;            // b*62 + i   (992 blocks)
  const int b = blk / 62, i = blk - b * 62;
  const int tid = threadIdx.x;
  const int wave = tid >> 6, lane = tid & 63;
  const int q = lane >> 4, ln = lane & 15;

  const unsigned char* fspl = ws + FSPL_OFF;
  const unsigned char* fsil = ws + FSILU_OFF;
  const unsigned char* wp   = ws + WPACK_OFF + (size_t)lane * 16;

  // per-lane spline feature offsets for the 9 steps of each period
  int voff[9];
#pragma unroll
  for (int sg = 0; sg < 9; ++sg) {
    int rid = 4 * sg + q;
    int ch = rid / 3;
    int sub = rid - ch * 3;
    int coff = ch / 3;
    int di = ch - coff * 3;
    voff[sg] = coff * 65536 + di * 1024 + sub * 16 + ln * 16;
  }

  v4f acc[4][4];
#pragma unroll
  for (int a = 0; a < 4; ++a)
#pragma unroll
    for (int c = 0; c < 4; ++c) acc[a][c] = (v4f){0.f, 0.f, 0.f, 0.f};

  // ---- spline phase: this wave's 18 steps (periods 2w, 2w+1), depth-2 pipe -
  const int P0 = wave * 2;
  const unsigned char* sb = fspl + (size_t)(b * 2048 + i) * 1024 + (size_t)P0 * 262144;
  const unsigned char* wp0 = wp + (size_t)(P0 * 9) * 4096;

  v8s wb[2][4], fb[2][4];
  {
#pragma unroll
    for (int ot = 0; ot < 4; ++ot) wb[0][ot] = *(const v8s*)(wp0 + ot * 1024);
    const unsigned char* p = sb + voff[0];
#pragma unroll
    for (int pt = 0; pt < 4; ++pt) fb[0][pt] = *(const v8s*)(p + pt * 256);
  }

#pragma unroll
  for (int idx = 0; idx < 18; ++idx) {
    const int cur = idx & 1, nxt = cur ^ 1;
    if (idx + 1 < 18) {
      const int sg1 = (idx + 1) % 9;           // compile-time
      const int pp  = (idx + 1) / 9;           // 0 or 1
      const unsigned char* wpp = wp0 + (size_t)(idx + 1) * 4096;
#pragma unroll
      for (int ot = 0; ot < 4; ++ot) wb[nxt][ot] = *(const v8s*)(wpp + ot * 1024);
      const unsigned char* p = sb + (size_t)pp * 262144 + voff[sg1];
#pragma unroll
      for (int pt = 0; pt < 4; ++pt) fb[nxt][pt] = *(const v8s*)(p + pt * 256);
    }
#pragma unroll
    for (int ot = 0; ot < 4; ++ot)
#pragma unroll
      for (int pt = 0; pt < 4; ++pt)
        acc[ot][pt] = __builtin_amdgcn_mfma_f32_16x16x32_bf16(
            wb[cur][ot], fb[cur][pt], acc[ot][pt], 0, 0, 0);
  }

  // ---- silu phase: waves 0..2 take steps 72+3w .. 72+3w+2 (di=w, dj=e) -----
  if (wave < 3) {
    const unsigned char* wps = wp + (size_t)(72 + 3 * wave) * 4096;
    const unsigned char* fsb =
        fsil + (size_t)((b * 64 + i + wave) * 64) * 64 + (size_t)ln * 64 + q * 16;
    {
#pragma unroll
      for (int ot = 0; ot < 4; ++ot) wb[0][ot] = *(const v8s*)(wps + ot * 1024);
#pragma unroll
      for (int pt = 0; pt < 4; ++pt) fb[0][pt] = *(const v8s*)(fsb + pt * 1024);
    }
#pragma unroll
    for (int e = 0; e < 3; ++e) {
      const int cur = e & 1, nxt = cur ^ 1;
      if (e + 1 < 3) {
        const unsigned char* wpp = wps + (size_t)(e + 1) * 4096;
#pragma unroll
        for (int ot = 0; ot < 4; ++ot) wb[nxt][ot] = *(const v8s*)(wpp + ot * 1024);
        const unsigned char* p = fsb + (size_t)(e + 1) * 64;
#pragma unroll
        for (int pt = 0; pt < 4; ++pt) fb[nxt][pt] = *(const v8s*)(p + pt * 1024);
      }
#pragma unroll
      for (int ot = 0; ot < 4; ++ot)
#pragma unroll
        for (int pt = 0; pt < 4; ++pt)
          acc[ot][pt] = __builtin_amdgcn_mfma_f32_16x16x32_bf16(
              wb[cur][ot], fb[cur][pt], acc[ot][pt], 0, 0, 0);
    }
  }

  // ---- reduction: pairwise tree through 32 KB LDS --------------------------
  __shared__ float red[8192];
  if (wave >= 2) {
    float* dst = red + (wave - 2) * 4096 + lane * 4;
#pragma unroll
    for (int ot = 0; ot < 4; ++ot)
#pragma unroll
      for (int pt = 0; pt < 4; ++pt)
        *(v4f*)(dst + (ot * 4 + pt) * 256) = acc[ot][pt];
  }
  __syncthreads();
  if (wave < 2) {
    const float* srcp = red + wave * 4096 + lane * 4;
#pragma unroll
    for (int ot = 0; ot < 4; ++ot)
#pragma unroll
      for (int pt = 0; pt < 4; ++pt)
        acc[ot][pt] += *(const v4f*)(srcp + (ot * 4 + pt) * 256);
  }
  __syncthreads();
  if (wave == 1) {
    float* dst = red + lane * 4;
#pragma unroll
    for (int ot = 0; ot < 4; ++ot)
#pragma unroll
      for (int pt = 0; pt < 4; ++pt)
        *(v4f*)(dst + (ot * 4 + pt) * 256) = acc[ot][pt];
  }
  __syncthreads();
  if (wave == 0) {
    const float* srcp = red + lane * 4;
#pragma unroll
    for (int ot = 0; ot < 4; ++ot)
#pragma unroll
      for (int pt = 0; pt < 4; ++pt)
        acc[ot][pt] += *(const v4f*)(srcp + (ot * 4 + pt) * 256);

    // C/D layout: col(n=j)=lane&15, row(m=o)=q*4+reg
#pragma unroll
    for (int ot = 0; ot < 4; ++ot)
#pragma unroll
      for (int pt = 0; pt < 4; ++pt) {
        const int j = pt * 16 + ln;
        if (j < 62) {
#pragma unroll
          for (int r = 0; r < 4; ++r) {
            const int o = ot * 16 + q * 4 + r;
            out[(((size_t)b * 64 + o) * 62 + i) * 62 + j] = acc[ot][pt][r];
          }
        }
      }
  }
}

extern "C" void kernel_launch(void* const* d_in, const int* in_sizes, int n_in,
                              void* d_out, int out_size, void* d_ws, size_t ws_size,
                              hipStream_t stream) {
  const float* x  = (const float*)d_in[0];
  const float* bw = (const float*)d_in[1];
  const float* sw = (const float*)d_in[2];
  const float* sc = (const float*)d_in[3];
  unsigned char* ws = (unsigned char*)d_ws;
  float* out = (float*)d_out;

  hipLaunchKernelGGL(k_spline, dim3(8192), dim3(256), 0, stream, x, ws);
  hipLaunchKernelGGL(k_silu,   dim3(1024), dim3(256), 0, stream, x, ws);
  hipLaunchKernelGGL(k_wpack,  dim3(648),  dim3(256), 0, stream, bw, sw, sc, ws);
  hipLaunchKernelGGL(k_gemm,   dim3(992),  dim3(256), 0, stream, ws, out);
}